// Round 2
// baseline (779.704 us; speedup 1.0000x reference)
//
#include <hip/hip_runtime.h>

typedef float f32x4 __attribute__((ext_vector_type(4)));
typedef short short8 __attribute__((ext_vector_type(8)));

#define M_DIM 4096
#define B_SZ 4
#define NCOL 8
#define HID 240
#define R2 (B_SZ * HID)          // 960

// bf16 round-to-nearest-even (inputs are finite normals; no NaN handling needed)
__device__ __forceinline__ unsigned short bf16_rne(float f) {
    unsigned u = __float_as_uint(f);
    return (unsigned short)((u + 0x7FFFu + ((u >> 16) & 1u)) >> 16);
}
__device__ __forceinline__ float bf16_to_f(unsigned short h) {
    return __uint_as_float(((unsigned)h) << 16);
}

// ---------------------------------------------------------------------------
// prep: combine theta[...,0]+theta[...,1] -> W, theta[...,2] -> V
// ---------------------------------------------------------------------------
__global__ __launch_bounds__(256) void prep_weights(
    const float* __restrict__ t1, const float* __restrict__ t2,
    const float* __restrict__ t3,
    float* __restrict__ Wc1, float* __restrict__ Vc1,
    float* __restrict__ Wc2, float* __restrict__ Vc2,
    float* __restrict__ Wc3, float* __restrict__ Vc3)
{
    const int n1 = HID * NCOL, n2 = HID * HID, n3 = NCOL * HID;
    int idx = blockIdx.x * blockDim.x + threadIdx.x;
    if (idx < n1) {
        const float* p = t1 + (size_t)idx * 3;
        Wc1[idx] = p[0] + p[1]; Vc1[idx] = p[2];
    } else if (idx < n1 + n2) {
        int j = idx - n1;
        const float* p = t2 + (size_t)j * 3;
        Wc2[j] = p[0] + p[1]; Vc2[j] = p[2];
    } else if (idx < n1 + n2 + n3) {
        int j = idx - n1 - n2;
        const float* p = t3 + (size_t)j * 3;
        Wc3[j] = p[0] + p[1]; Vc3[j] = p[2];
    }
}

// ---------------------------------------------------------------------------
// split_lu: Lu fp32 -> (hi, lo) bf16.  16.7M elems, 8/thread.
// ---------------------------------------------------------------------------
__global__ __launch_bounds__(256) void split_lu(
    const float* __restrict__ Lu, short* __restrict__ Lh, short* __restrict__ Ll)
{
    size_t i8 = ((size_t)blockIdx.x * 256 + threadIdx.x) * 8;
    float4 a = *(const float4*)(Lu + i8);
    float4 b = *(const float4*)(Lu + i8 + 4);
    float v[8] = {a.x, a.y, a.z, a.w, b.x, b.y, b.z, b.w};
    short8 h, l;
    #pragma unroll
    for (int e = 0; e < 8; ++e) {
        unsigned short hb = bf16_rne(v[e]);
        h[e] = (short)hb;
        l[e] = (short)bf16_rne(v[e] - bf16_to_f(hb));
    }
    *(short8*)(Lh + i8) = h;
    *(short8*)(Ll + i8) = l;
}

// ---------------------------------------------------------------------------
// split_x: x (32 x 4096) -> hi/lo bf16 padded to 64 rows (pad rows zero).
// ---------------------------------------------------------------------------
__global__ __launch_bounds__(256) void split_x(
    const float* __restrict__ x, short* __restrict__ Xh, short* __restrict__ Xl)
{
    int t = blockIdx.x * 256 + threadIdx.x;      // 0..32767 (64*4096/8)
    size_t i8 = (size_t)t * 8;
    int row = t >> 9;                            // 512 chunks per 4096-row
    short8 h = {0,0,0,0,0,0,0,0}, l = {0,0,0,0,0,0,0,0};
    if (row < B_SZ * NCOL) {
        float4 a = *(const float4*)(x + i8);
        float4 b = *(const float4*)(x + i8 + 4);
        float v[8] = {a.x, a.y, a.z, a.w, b.x, b.y, b.z, b.w};
        #pragma unroll
        for (int e = 0; e < 8; ++e) {
            unsigned short hb = bf16_rne(v[e]);
            h[e] = (short)hb;
            l[e] = (short)bf16_rne(v[e] - bf16_to_f(hb));
        }
    }
    *(short8*)(Xh + i8) = h;
    *(short8*)(Xl + i8) = l;
}

// ---------------------------------------------------------------------------
// gemm_split: C[r,m] = sum_k (Ah+Al)[r,k] * (Bh+Bl)[m,k]  (3-term bf16 split)
// C fp32. Tile 64(M-rows) x 128(N-cols) x 64(K). 256 thr = 4 waves (2x2),
// wave tile 32x64. LDS chunk layout c = r*8 + ((kg+r)&7): bank-balanced
// ds_read_b128 AND linear dest for global_load_lds (permutation folded into
// per-lane global source address).
// ---------------------------------------------------------------------------
#define GBM 64
#define GBN 128
#define GBK 64

__global__ __launch_bounds__(256, 2) void gemm_split(
    const short* __restrict__ Ah, const short* __restrict__ Al,
    const short* __restrict__ Bh, const short* __restrict__ Bl,
    float* __restrict__ C, int R, int NY)
{
    // Ah/Al: 512 chunks (8KB) each; Bh/Bl: 1024 chunks (16KB) each. 48KB total.
    __shared__ short8 lds[3072];
    short8* sAh = lds;
    short8* sAl = lds + 512;
    short8* sBh = lds + 1024;
    short8* sBl = lds + 2048;

    const int tid  = threadIdx.x;
    const int w    = tid >> 6;
    const int lane = tid & 63;
    const int wr   = w >> 1, wc = w & 1;

    // XCD-chunk swizzle (grid always divisible by 8) + col-tile-major decompose
    int chunk = gridDim.x >> 3;
    int bid = (blockIdx.x & 7) * chunk + (blockIdx.x >> 3);
    int bx = bid / NY;           // col tile (N)
    int by = bid % NY;           // row tile (M)
    const int r0 = by * GBM;
    const int m0 = bx * GBN;

    // ---- staging descriptors: 12 wave-calls of 64 chunks each -------------
    const short* gp[12];
    short8* lp[12];
    #pragma unroll
    for (int j = 0; j < 12; ++j) {
        int g = w * 12 + j;                    // 0..47 global call id
        const short* base; int c0, row0, seg;
        if (g < 8)       { base = Ah; c0 = g * 64;        row0 = r0; seg = 0;    }
        else if (g < 16) { base = Al; c0 = (g - 8) * 64;  row0 = r0; seg = 512;  }
        else if (g < 32) { base = Bh; c0 = (g - 16) * 64; row0 = m0; seg = 1024; }
        else             { base = Bl; c0 = (g - 32) * 64; row0 = m0; seg = 2048; }
        int c  = c0 + lane;
        int r  = c >> 3;
        int kg = ((c & 7) - r) & 7;
        gp[j] = base + (size_t)(row0 + r) * M_DIM + kg * 8;
        lp[j] = &lds[seg + c0];
    }

    // ---- fragment LDS chunk indices (K-step invariant) --------------------
    int cA[2][2], cB[2][4];
    #pragma unroll
    for (int s = 0; s < 2; ++s) {
        int kgl = s * 4 + (lane >> 4);
        #pragma unroll
        for (int mi = 0; mi < 2; ++mi) {
            int r = wr * 32 + mi * 16 + (lane & 15);
            cA[s][mi] = r * 8 + ((kgl + r) & 7);
        }
        #pragma unroll
        for (int nj = 0; nj < 4; ++nj) {
            int r = wc * 64 + nj * 16 + (lane & 15);
            cB[s][nj] = r * 8 + ((kgl + r) & 7);
        }
    }

    f32x4 acc[2][4] = {};

    for (int k0 = 0; k0 < M_DIM; k0 += GBK) {
        #pragma unroll
        for (int j = 0; j < 12; ++j)
            __builtin_amdgcn_global_load_lds(
                (const __attribute__((address_space(1))) void*)(gp[j] + k0),
                (__attribute__((address_space(3))) void*)(lp[j]), 16, 0, 0);
        __syncthreads();

        #pragma unroll
        for (int s = 0; s < 2; ++s) {
            short8 ahf[2], alf[2], bhf[4], blf[4];
            #pragma unroll
            for (int mi = 0; mi < 2; ++mi) {
                ahf[mi] = sAh[cA[s][mi]];
                alf[mi] = sAl[cA[s][mi]];
            }
            #pragma unroll
            for (int nj = 0; nj < 4; ++nj) {
                bhf[nj] = sBh[cB[s][nj]];
                blf[nj] = sBl[cB[s][nj]];
            }
            #pragma unroll
            for (int mi = 0; mi < 2; ++mi)
                #pragma unroll
                for (int nj = 0; nj < 4; ++nj) {
                    acc[mi][nj] = __builtin_amdgcn_mfma_f32_16x16x32_bf16(
                        ahf[mi], bhf[nj], acc[mi][nj], 0, 0, 0);
                    acc[mi][nj] = __builtin_amdgcn_mfma_f32_16x16x32_bf16(
                        ahf[mi], blf[nj], acc[mi][nj], 0, 0, 0);
                    acc[mi][nj] = __builtin_amdgcn_mfma_f32_16x16x32_bf16(
                        alf[mi], bhf[nj], acc[mi][nj], 0, 0, 0);
                }
        }
        __syncthreads();
    }

    // ---- epilogue: D row=(lane>>4)*4+q, col=lane&15 (m89-verified) --------
    const int colb = m0 + wc * 64 + (lane & 15);
    #pragma unroll
    for (int mi = 0; mi < 2; ++mi) {
        int rowb = r0 + wr * 32 + mi * 16 + ((lane >> 4) << 2);
        #pragma unroll
        for (int nj = 0; nj < 4; ++nj)
            #pragma unroll
            for (int q = 0; q < 4; ++q) {
                int row = rowb + q;
                if (row < R)
                    C[(size_t)row * M_DIM + colb + nj * 16] = acc[mi][nj][q];
            }
    }
}

// ---------------------------------------------------------------------------
// mix1: H1 = lrelu(bias1 + W1*x + V1*Z1), fused bf16 hi/lo split of H1.
// ---------------------------------------------------------------------------
__global__ __launch_bounds__(256) void mix1(
    const float* __restrict__ x, const float* __restrict__ Z1,
    const float* __restrict__ Wc1, const float* __restrict__ Vc1,
    const float* __restrict__ bias1,
    float* __restrict__ H1, short* __restrict__ H1h, short* __restrict__ H1l)
{
    __shared__ float w[HID * NCOL], v[HID * NCOL], bb[HID];
    for (int i = threadIdx.x; i < HID * NCOL; i += 256) { w[i] = Wc1[i]; v[i] = Vc1[i]; }
    for (int i = threadIdx.x; i < HID; i += 256) bb[i] = bias1[i];
    __syncthreads();

    int gm = blockIdx.x * 256 + threadIdx.x;   // 0..B*M-1
    int b = gm / M_DIM, m = gm % M_DIM;

    float xv[NCOL], lv[NCOL];
    #pragma unroll
    for (int i = 0; i < NCOL; ++i) {
        xv[i] = x[((size_t)b * NCOL + i) * M_DIM + m];
        lv[i] = Z1[((size_t)b * NCOL + i) * M_DIM + m];
    }
    for (int o = 0; o < HID; ++o) {
        float acc = bb[o];
        #pragma unroll
        for (int i = 0; i < NCOL; ++i)
            acc += w[o * NCOL + i] * xv[i] + v[o * NCOL + i] * lv[i];
        acc = acc > 0.f ? acc : 0.01f * acc;
        size_t idx = ((size_t)b * HID + o) * M_DIM + m;
        H1[idx] = acc;
        unsigned short hb = bf16_rne(acc);
        H1h[idx] = (short)hb;
        H1l[idx] = (short)bf16_rne(acc - bf16_to_f(hb));
    }
}

// ---------------------------------------------------------------------------
// mix2: H2 = lrelu(bias2 + W2*H1 + V2*Z2), fused hi/lo split of H2.
// ---------------------------------------------------------------------------
#define MT 32
__global__ __launch_bounds__(256) void mix2(
    const float* __restrict__ H1, const float* __restrict__ Z2,
    const float* __restrict__ Wc2, const float* __restrict__ Vc2,
    const float* __restrict__ bias2,
    float* __restrict__ H2, short* __restrict__ H2h, short* __restrict__ H2l)
{
    __shared__ float hs[HID][MT];
    __shared__ float zs[HID][MT];
    const int b = blockIdx.y;
    const int m0 = blockIdx.x * MT;

    for (int idx = threadIdx.x; idx < HID * MT; idx += 256) {
        int i = idx / MT, mm = idx % MT;
        hs[i][mm] = H1[((size_t)b * HID + i) * M_DIM + m0 + mm];
        zs[i][mm] = Z2[((size_t)b * HID + i) * M_DIM + m0 + mm];
    }
    __syncthreads();

    const int mm = threadIdx.x & 31;
    const int og = threadIdx.x >> 5;               // 0..7
    for (int oj = 0; oj < HID / 8; ++oj) {         // 30 outputs/thread
        int o = og * (HID / 8) + oj;
        float acc = bias2[o];
        const float* wr_ = Wc2 + (size_t)o * HID;
        const float* vr_ = Vc2 + (size_t)o * HID;
        #pragma unroll 4
        for (int i = 0; i < HID; ++i)
            acc += wr_[i] * hs[i][mm] + vr_[i] * zs[i][mm];
        acc = acc > 0.f ? acc : 0.01f * acc;
        size_t idx = ((size_t)b * HID + o) * M_DIM + m0 + mm;
        H2[idx] = acc;
        unsigned short hb = bf16_rne(acc);
        H2h[idx] = (short)hb;
        H2l[idx] = (short)bf16_rne(acc - bf16_to_f(hb));
    }
}

// ---------------------------------------------------------------------------
// mix3: out = bias3 + W3*H2 + V3*Z3   (no activation)
// ---------------------------------------------------------------------------
__global__ __launch_bounds__(256) void mix3(
    const float* __restrict__ H2, const float* __restrict__ Z3,
    const float* __restrict__ Wc3, const float* __restrict__ Vc3,
    const float* __restrict__ bias3, float* __restrict__ out)
{
    __shared__ float w[NCOL * HID], v[NCOL * HID];
    for (int i = threadIdx.x; i < NCOL * HID; i += 256) { w[i] = Wc3[i]; v[i] = Vc3[i]; }
    __syncthreads();

    int gm = blockIdx.x * 256 + threadIdx.x;
    int b = gm / M_DIM, m = gm % M_DIM;

    float acc[NCOL];
    #pragma unroll
    for (int c = 0; c < NCOL; ++c) acc[c] = bias3[c];

    for (int i = 0; i < HID; ++i) {
        float h = H2[((size_t)b * HID + i) * M_DIM + m];
        float z = Z3[((size_t)b * HID + i) * M_DIM + m];
        #pragma unroll
        for (int c = 0; c < NCOL; ++c)
            acc[c] += w[c * HID + i] * h + v[c * HID + i] * z;
    }
    #pragma unroll
    for (int c = 0; c < NCOL; ++c)
        out[((size_t)b * NCOL + c) * M_DIM + m] = acc[c];
}

// ---------------------------------------------------------------------------
extern "C" void kernel_launch(void* const* d_in, const int* in_sizes, int n_in,
                              void* d_out, int out_size, void* d_ws, size_t ws_size,
                              hipStream_t stream)
{
    // inputs: Ll, Lu, x, theta1, bias1, theta2, bias2, theta3, bias3
    const float* Lu = (const float*)d_in[1];
    const float* x  = (const float*)d_in[2];
    const float* t1 = (const float*)d_in[3];
    const float* b1 = (const float*)d_in[4];
    const float* t2 = (const float*)d_in[5];
    const float* b2 = (const float*)d_in[6];
    const float* t3 = (const float*)d_in[7];
    const float* b3 = (const float*)d_in[8];
    float* out = (float*)d_out;

    // workspace carve-up (256B aligned)
    char* p = (char*)d_ws;
    auto carve = [&](size_t bytes) { char* r = p; p += (bytes + 255) & ~(size_t)255; return r; };
    short* Luh = (short*)carve((size_t)M_DIM * M_DIM * 2);
    short* Lul = (short*)carve((size_t)M_DIM * M_DIM * 2);
    short* Xh  = (short*)carve((size_t)64 * M_DIM * 2);
    short* Xl  = (short*)carve((size_t)64 * M_DIM * 2);
    float* Z1  = (float*)carve((size_t)32 * M_DIM * 4);
    float* H1  = (float*)carve((size_t)R2 * M_DIM * 4);
    short* H1h = (short*)carve((size_t)R2 * M_DIM * 2);
    short* H1l = (short*)carve((size_t)R2 * M_DIM * 2);
    float* Z2  = (float*)carve((size_t)R2 * M_DIM * 4);
    float* H2  = (float*)carve((size_t)R2 * M_DIM * 4);
    short* H2h = (short*)carve((size_t)R2 * M_DIM * 2);
    short* H2l = (short*)carve((size_t)R2 * M_DIM * 2);
    float* Z3  = H1;   // H1 (fp32) dead after mix2
    float* Wc1 = (float*)carve(HID * NCOL * 4);
    float* Vc1 = (float*)carve(HID * NCOL * 4);
    float* Wc2 = (float*)carve(HID * HID * 4);
    float* Vc2 = (float*)carve(HID * HID * 4);
    float* Wc3 = (float*)carve(NCOL * HID * 4);
    float* Vc3 = (float*)carve(NCOL * HID * 4);

    prep_weights<<<240, 256, 0, stream>>>(t1, t2, t3, Wc1, Vc1, Wc2, Vc2, Wc3, Vc3);
    split_lu<<<(M_DIM * M_DIM) / (256 * 8), 256, 0, stream>>>(Lu, Luh, Lul);
    split_x<<<(64 * M_DIM) / (256 * 8), 256, 0, stream>>>(x, Xh, Xl);

    // layer 1: Z1 = x @ Lu^T   (grid 32x1 -> 32 blocks)
    gemm_split<<<(M_DIM / GBN) * 1, 256, 0, stream>>>(Xh, Xl, Luh, Lul, Z1, 32, 1);
    mix1<<<(B_SZ * M_DIM) / 256, 256, 0, stream>>>(x, Z1, Wc1, Vc1, b1, H1, H1h, H1l);

    // layer 2: Z2 = H1 @ Lu^T  (grid 32x15 -> 480 blocks)
    gemm_split<<<(M_DIM / GBN) * (R2 / GBM), 256, 0, stream>>>(H1h, H1l, Luh, Lul, Z2, R2, R2 / GBM);
    mix2<<<dim3(M_DIM / MT, B_SZ), 256, 0, stream>>>(H1, Z2, Wc2, Vc2, b2, H2, H2h, H2l);

    // layer 3: Z3 = H2 @ Lu^T
    gemm_split<<<(M_DIM / GBN) * (R2 / GBM), 256, 0, stream>>>(H2h, H2l, Luh, Lul, Z3, R2, R2 / GBM);
    mix3<<<(B_SZ * M_DIM) / 256, 256, 0, stream>>>(H2, Z3, Wc3, Vc3, b3, out);
}

// Round 5
// 640.049 us; speedup vs baseline: 1.2182x; 1.2182x over previous
//
#include <hip/hip_runtime.h>

typedef float f32x4 __attribute__((ext_vector_type(4)));
typedef short short8 __attribute__((ext_vector_type(8)));

#define M_DIM 4096
#define B_SZ 4
#define NCOL 8
#define HID 240
#define R2 (B_SZ * HID)          // 960

// bf16 round-to-nearest-even (inputs are finite normals; no NaN handling needed)
__device__ __forceinline__ unsigned short bf16_rne(float f) {
    unsigned u = __float_as_uint(f);
    return (unsigned short)((u + 0x7FFFu + ((u >> 16) & 1u)) >> 16);
}
__device__ __forceinline__ float bf16_to_f(unsigned short h) {
    return __uint_as_float(((unsigned)h) << 16);
}

// ---------------------------------------------------------------------------
// prep: combine theta[...,0]+theta[...,1] -> W, theta[...,2] -> V
// ---------------------------------------------------------------------------
__global__ __launch_bounds__(256) void prep_weights(
    const float* __restrict__ t1, const float* __restrict__ t2,
    const float* __restrict__ t3,
    float* __restrict__ Wc1, float* __restrict__ Vc1,
    float* __restrict__ Wc2, float* __restrict__ Vc2,
    float* __restrict__ Wc3, float* __restrict__ Vc3)
{
    const int n1 = HID * NCOL, n2 = HID * HID, n3 = NCOL * HID;
    int idx = blockIdx.x * blockDim.x + threadIdx.x;
    if (idx < n1) {
        const float* p = t1 + (size_t)idx * 3;
        Wc1[idx] = p[0] + p[1]; Vc1[idx] = p[2];
    } else if (idx < n1 + n2) {
        int j = idx - n1;
        const float* p = t2 + (size_t)j * 3;
        Wc2[j] = p[0] + p[1]; Vc2[j] = p[2];
    } else if (idx < n1 + n2 + n3) {
        int j = idx - n1 - n2;
        const float* p = t3 + (size_t)j * 3;
        Wc3[j] = p[0] + p[1]; Vc3[j] = p[2];
    }
}

// ---------------------------------------------------------------------------
// split_lu: Lu fp32 -> (hi, lo) bf16.  16.7M elems, 8/thread.
// ---------------------------------------------------------------------------
__global__ __launch_bounds__(256) void split_lu(
    const float* __restrict__ Lu, short* __restrict__ Lh, short* __restrict__ Ll)
{
    size_t i8 = ((size_t)blockIdx.x * 256 + threadIdx.x) * 8;
    float4 a = *(const float4*)(Lu + i8);
    float4 b = *(const float4*)(Lu + i8 + 4);
    float v[8] = {a.x, a.y, a.z, a.w, b.x, b.y, b.z, b.w};
    short8 h, l;
    #pragma unroll
    for (int e = 0; e < 8; ++e) {
        unsigned short hb = bf16_rne(v[e]);
        h[e] = (short)hb;
        l[e] = (short)bf16_rne(v[e] - bf16_to_f(hb));
    }
    *(short8*)(Lh + i8) = h;
    *(short8*)(Ll + i8) = l;
}

// ---------------------------------------------------------------------------
// split_x: x (32 x 4096) -> hi/lo bf16 padded to 64 rows (pad rows zero).
// ---------------------------------------------------------------------------
__global__ __launch_bounds__(256) void split_x(
    const float* __restrict__ x, short* __restrict__ Xh, short* __restrict__ Xl)
{
    int t = blockIdx.x * 256 + threadIdx.x;      // 0..32767 (64*4096/8)
    size_t i8 = (size_t)t * 8;
    int row = t >> 9;                            // 512 chunks per 4096-row
    short8 h = {0,0,0,0,0,0,0,0}, l = {0,0,0,0,0,0,0,0};
    if (row < B_SZ * NCOL) {
        float4 a = *(const float4*)(x + i8);
        float4 b = *(const float4*)(x + i8 + 4);
        float v[8] = {a.x, a.y, a.z, a.w, b.x, b.y, b.z, b.w};
        #pragma unroll
        for (int e = 0; e < 8; ++e) {
            unsigned short hb = bf16_rne(v[e]);
            h[e] = (short)hb;
            l[e] = (short)bf16_rne(v[e] - bf16_to_f(hb));
        }
    }
    *(short8*)(Xh + i8) = h;
    *(short8*)(Xl + i8) = l;
}

// ---------------------------------------------------------------------------
// gemm_split: C[r,m] = sum_k (Ah+Al)[r,k] * (Bh+Bl)[m,k]  (3-term bf16 split)
// C fp32. Tile 64(M-rows) x 128(N-cols) x 64(K). 256 thr = 4 waves (2x2),
// wave tile 32x64. LDS chunk layout c = r*8 + ((kg+r)&7): bank-balanced
// ds_read_b128 AND linear dest for global_load_lds (permutation folded into
// per-lane global source address).
// ---------------------------------------------------------------------------
#define GBM 64
#define GBN 128
#define GBK 64

__global__ __launch_bounds__(256, 2) void gemm_split(
    const short* __restrict__ Ah, const short* __restrict__ Al,
    const short* __restrict__ Bh, const short* __restrict__ Bl,
    float* __restrict__ C, int R, int NY)
{
    // Ah/Al: 512 chunks (8KB) each; Bh/Bl: 1024 chunks (16KB) each. 48KB total.
    __shared__ short8 lds[3072];
    short8* sAh = lds;
    short8* sAl = lds + 512;
    short8* sBh = lds + 1024;
    short8* sBl = lds + 2048;

    const int tid  = threadIdx.x;
    const int w    = tid >> 6;
    const int lane = tid & 63;
    const int wr   = w >> 1, wc = w & 1;

    // XCD-chunk swizzle (grid always divisible by 8) + col-tile-major decompose
    int chunk = gridDim.x >> 3;
    int bid = (blockIdx.x & 7) * chunk + (blockIdx.x >> 3);
    int bx = bid / NY;           // col tile (N)
    int by = bid % NY;           // row tile (M)
    const int r0 = by * GBM;
    const int m0 = bx * GBN;

    // ---- staging descriptors: 12 wave-calls of 64 chunks each -------------
    const short* gp[12];
    short8* lp[12];
    #pragma unroll
    for (int j = 0; j < 12; ++j) {
        int g = w * 12 + j;                    // 0..47 global call id
        const short* base; int c0, row0, seg;
        if (g < 8)       { base = Ah; c0 = g * 64;        row0 = r0; seg = 0;    }
        else if (g < 16) { base = Al; c0 = (g - 8) * 64;  row0 = r0; seg = 512;  }
        else if (g < 32) { base = Bh; c0 = (g - 16) * 64; row0 = m0; seg = 1024; }
        else             { base = Bl; c0 = (g - 32) * 64; row0 = m0; seg = 2048; }
        int c  = c0 + lane;
        int r  = c >> 3;
        int kg = ((c & 7) - r) & 7;
        gp[j] = base + (size_t)(row0 + r) * M_DIM + kg * 8;
        lp[j] = &lds[seg + c0];
    }

    // ---- fragment LDS chunk indices (K-step invariant) --------------------
    int cA[2][2], cB[2][4];
    #pragma unroll
    for (int s = 0; s < 2; ++s) {
        int kgl = s * 4 + (lane >> 4);
        #pragma unroll
        for (int mi = 0; mi < 2; ++mi) {
            int r = wr * 32 + mi * 16 + (lane & 15);
            cA[s][mi] = r * 8 + ((kgl + r) & 7);
        }
        #pragma unroll
        for (int nj = 0; nj < 4; ++nj) {
            int r = wc * 64 + nj * 16 + (lane & 15);
            cB[s][nj] = r * 8 + ((kgl + r) & 7);
        }
    }

    f32x4 acc[2][4] = {};

    for (int k0 = 0; k0 < M_DIM; k0 += GBK) {
        #pragma unroll
        for (int j = 0; j < 12; ++j)
            __builtin_amdgcn_global_load_lds(
                (const __attribute__((address_space(1))) void*)(gp[j] + k0),
                (__attribute__((address_space(3))) void*)(lp[j]), 16, 0, 0);
        __syncthreads();

        #pragma unroll
        for (int s = 0; s < 2; ++s) {
            short8 ahf[2], alf[2], bhf[4], blf[4];
            #pragma unroll
            for (int mi = 0; mi < 2; ++mi) {
                ahf[mi] = sAh[cA[s][mi]];
                alf[mi] = sAl[cA[s][mi]];
            }
            #pragma unroll
            for (int nj = 0; nj < 4; ++nj) {
                bhf[nj] = sBh[cB[s][nj]];
                blf[nj] = sBl[cB[s][nj]];
            }
            #pragma unroll
            for (int mi = 0; mi < 2; ++mi)
                #pragma unroll
                for (int nj = 0; nj < 4; ++nj) {
                    acc[mi][nj] = __builtin_amdgcn_mfma_f32_16x16x32_bf16(
                        ahf[mi], bhf[nj], acc[mi][nj], 0, 0, 0);
                    acc[mi][nj] = __builtin_amdgcn_mfma_f32_16x16x32_bf16(
                        ahf[mi], blf[nj], acc[mi][nj], 0, 0, 0);
                    acc[mi][nj] = __builtin_amdgcn_mfma_f32_16x16x32_bf16(
                        alf[mi], bhf[nj], acc[mi][nj], 0, 0, 0);
                }
        }
        __syncthreads();
    }

    // ---- epilogue: D row=(lane>>4)*4+q, col=lane&15 (m89-verified) --------
    const int colb = m0 + wc * 64 + (lane & 15);
    #pragma unroll
    for (int mi = 0; mi < 2; ++mi) {
        int rowb = r0 + wr * 32 + mi * 16 + ((lane >> 4) << 2);
        #pragma unroll
        for (int nj = 0; nj < 4; ++nj)
            #pragma unroll
            for (int q = 0; q < 4; ++q) {
                int row = rowb + q;
                if (row < R)
                    C[(size_t)row * M_DIM + colb + nj * 16] = acc[mi][nj][q];
            }
    }
}

// ---------------------------------------------------------------------------
// mix1: H1 = lrelu(bias1 + W1*x + V1*Z1), fused bf16 hi/lo split of H1.
// ---------------------------------------------------------------------------
__global__ __launch_bounds__(256) void mix1(
    const float* __restrict__ x, const float* __restrict__ Z1,
    const float* __restrict__ Wc1, const float* __restrict__ Vc1,
    const float* __restrict__ bias1,
    float* __restrict__ H1, short* __restrict__ H1h, short* __restrict__ H1l)
{
    __shared__ float w[HID * NCOL], v[HID * NCOL], bb[HID];
    for (int i = threadIdx.x; i < HID * NCOL; i += 256) { w[i] = Wc1[i]; v[i] = Vc1[i]; }
    for (int i = threadIdx.x; i < HID; i += 256) bb[i] = bias1[i];
    __syncthreads();

    int gm = blockIdx.x * 256 + threadIdx.x;   // 0..B*M-1
    int b = gm / M_DIM, m = gm % M_DIM;

    float xv[NCOL], lv[NCOL];
    #pragma unroll
    for (int i = 0; i < NCOL; ++i) {
        xv[i] = x[((size_t)b * NCOL + i) * M_DIM + m];
        lv[i] = Z1[((size_t)b * NCOL + i) * M_DIM + m];
    }
    for (int o = 0; o < HID; ++o) {
        float acc = bb[o];
        #pragma unroll
        for (int i = 0; i < NCOL; ++i)
            acc += w[o * NCOL + i] * xv[i] + v[o * NCOL + i] * lv[i];
        acc = acc > 0.f ? acc : 0.01f * acc;
        size_t idx = ((size_t)b * HID + o) * M_DIM + m;
        H1[idx] = acc;
        unsigned short hb = bf16_rne(acc);
        H1h[idx] = (short)hb;
        H1l[idx] = (short)bf16_rne(acc - bf16_to_f(hb));
    }
}

// ---------------------------------------------------------------------------
// mix2: register-tiled VALU GEMM.  C[o, b*4096+m] = bias2[o]
//       + sum_k W2[o,k]*H1[b,k,m] + V2[o,k]*Z2[b,k,m], lrelu, hi/lo split.
// Block: 256 thr (16 tx * 16 ty), tile 16*JN (o) x 128 (m), K-step 16.
// blockIdx.z selects o-half: z=0 -> JN=8 (o 0..127), z=1 -> JN=7 (o 128..239).
// Per thread: JN x 8 accumulators; per k: 2 LDS broadcasts + 4 b128 reads
// feed 16*JN FMAs (VALU-bound by design).
// ---------------------------------------------------------------------------
template<int JN>
__device__ __forceinline__ void mix2_body(
    const float* __restrict__ H1, const float* __restrict__ Z2,
    const float* __restrict__ Wc2, const float* __restrict__ Vc2,
    const float* __restrict__ bias2, int obase,
    float* __restrict__ H2, short* __restrict__ H2h, short* __restrict__ H2l,
    float (*Wt)[16], float (*Vt)[16], float (*hs)[128], float (*zs)[128])
{
    const int b  = blockIdx.y;
    const int m0 = blockIdx.x * 128;
    const int tx = threadIdx.x & 15;
    const int ty = threadIdx.x >> 4;

    float acc[JN][8] = {};

    for (int k0 = 0; k0 < HID; k0 += 16) {
        for (int idx = threadIdx.x; idx < JN * 16 * 16; idx += 256) {
            int row = idx >> 4, kk = idx & 15;
            Wt[row][kk] = Wc2[(size_t)(obase + row) * HID + k0 + kk];
            Vt[row][kk] = Vc2[(size_t)(obase + row) * HID + k0 + kk];
        }
        for (int idx = threadIdx.x; idx < 16 * 128; idx += 256) {
            int k = idx >> 7, mm = idx & 127;
            hs[k][mm] = H1[((size_t)b * HID + k0 + k) * M_DIM + m0 + mm];
            zs[k][mm] = Z2[((size_t)b * HID + k0 + k) * M_DIM + m0 + mm];
        }
        __syncthreads();

        #pragma unroll
        for (int k = 0; k < 16; ++k) {
            float4 h0 = *(const float4*)&hs[k][tx * 8];
            float4 h1 = *(const float4*)&hs[k][tx * 8 + 4];
            float4 z0 = *(const float4*)&zs[k][tx * 8];
            float4 z1 = *(const float4*)&zs[k][tx * 8 + 4];
            #pragma unroll
            for (int j = 0; j < JN; ++j) {
                float w = Wt[ty + 16 * j][k];
                float v = Vt[ty + 16 * j][k];
                acc[j][0] += w * h0.x + v * z0.x;
                acc[j][1] += w * h0.y + v * z0.y;
                acc[j][2] += w * h0.z + v * z0.z;
                acc[j][3] += w * h0.w + v * z0.w;
                acc[j][4] += w * h1.x + v * z1.x;
                acc[j][5] += w * h1.y + v * z1.y;
                acc[j][6] += w * h1.z + v * z1.z;
                acc[j][7] += w * h1.w + v * z1.w;
            }
        }
        __syncthreads();
    }

    #pragma unroll
    for (int j = 0; j < JN; ++j) {
        int o = obase + ty + 16 * j;
        float bb = bias2[o];
        size_t base = ((size_t)b * HID + o) * M_DIM + m0 + tx * 8;
        float r[8]; short8 hh, ll;
        #pragma unroll
        for (int e = 0; e < 8; ++e) {
            float a = acc[j][e] + bb;
            a = a > 0.f ? a : 0.01f * a;
            r[e] = a;
            unsigned short hb = bf16_rne(a);
            hh[e] = (short)hb;
            ll[e] = (short)bf16_rne(a - bf16_to_f(hb));
        }
        *(float4*)(H2 + base)     = make_float4(r[0], r[1], r[2], r[3]);
        *(float4*)(H2 + base + 4) = make_float4(r[4], r[5], r[6], r[7]);
        *(short8*)(H2h + base) = hh;
        *(short8*)(H2l + base) = ll;
    }
}

__global__ __launch_bounds__(256) void mix2(
    const float* __restrict__ H1, const float* __restrict__ Z2,
    const float* __restrict__ Wc2, const float* __restrict__ Vc2,
    const float* __restrict__ bias2,
    float* __restrict__ H2, short* __restrict__ H2h, short* __restrict__ H2l)
{
    __shared__ float Wt[128][16];
    __shared__ float Vt[128][16];
    __shared__ float hs[16][128];
    __shared__ float zs[16][128];

    if (blockIdx.z == 0)
        mix2_body<8>(H1, Z2, Wc2, Vc2, bias2, 0,   H2, H2h, H2l, Wt, Vt, hs, zs);
    else
        mix2_body<7>(H1, Z2, Wc2, Vc2, bias2, 128, H2, H2h, H2l, Wt, Vt, hs, zs);
}

// ---------------------------------------------------------------------------
// mix3: out = bias3 + W3*H2 + V3*Z3   (no activation)
// ---------------------------------------------------------------------------
__global__ __launch_bounds__(256) void mix3(
    const float* __restrict__ H2, const float* __restrict__ Z3,
    const float* __restrict__ Wc3, const float* __restrict__ Vc3,
    const float* __restrict__ bias3, float* __restrict__ out)
{
    __shared__ float w[NCOL * HID], v[NCOL * HID];
    for (int i = threadIdx.x; i < NCOL * HID; i += 256) { w[i] = Wc3[i]; v[i] = Vc3[i]; }
    __syncthreads();

    int gm = blockIdx.x * 256 + threadIdx.x;
    int b = gm / M_DIM, m = gm % M_DIM;

    float acc[NCOL];
    #pragma unroll
    for (int c = 0; c < NCOL; ++c) acc[c] = bias3[c];

    for (int i = 0; i < HID; ++i) {
        float h = H2[((size_t)b * HID + i) * M_DIM + m];
        float z = Z3[((size_t)b * HID + i) * M_DIM + m];
        #pragma unroll
        for (int c = 0; c < NCOL; ++c)
            acc[c] += w[c * HID + i] * h + v[c * HID + i] * z;
    }
    #pragma unroll
    for (int c = 0; c < NCOL; ++c)
        out[((size_t)b * NCOL + c) * M_DIM + m] = acc[c];
}

// ---------------------------------------------------------------------------
extern "C" void kernel_launch(void* const* d_in, const int* in_sizes, int n_in,
                              void* d_out, int out_size, void* d_ws, size_t ws_size,
                              hipStream_t stream)
{
    // inputs: Ll, Lu, x, theta1, bias1, theta2, bias2, theta3, bias3
    const float* Lu = (const float*)d_in[1];
    const float* x  = (const float*)d_in[2];
    const float* t1 = (const float*)d_in[3];
    const float* b1 = (const float*)d_in[4];
    const float* t2 = (const float*)d_in[5];
    const float* b2 = (const float*)d_in[6];
    const float* t3 = (const float*)d_in[7];
    const float* b3 = (const float*)d_in[8];
    float* out = (float*)d_out;

    // workspace carve-up (256B aligned)
    char* p = (char*)d_ws;
    auto carve = [&](size_t bytes) { char* r = p; p += (bytes + 255) & ~(size_t)255; return r; };
    short* Luh = (short*)carve((size_t)M_DIM * M_DIM * 2);
    short* Lul = (short*)carve((size_t)M_DIM * M_DIM * 2);
    short* Xh  = (short*)carve((size_t)64 * M_DIM * 2);
    short* Xl  = (short*)carve((size_t)64 * M_DIM * 2);
    float* Z1  = (float*)carve((size_t)32 * M_DIM * 4);
    float* H1  = (float*)carve((size_t)R2 * M_DIM * 4);
    short* H1h = (short*)carve((size_t)R2 * M_DIM * 2);
    short* H1l = (short*)carve((size_t)R2 * M_DIM * 2);
    float* Z2  = (float*)carve((size_t)R2 * M_DIM * 4);
    float* H2  = (float*)carve((size_t)R2 * M_DIM * 4);
    short* H2h = (short*)carve((size_t)R2 * M_DIM * 2);
    short* H2l = (short*)carve((size_t)R2 * M_DIM * 2);
    float* Z3  = H1;   // H1 (fp32) dead after mix2
    float* Wc1 = (float*)carve(HID * NCOL * 4);
    float* Vc1 = (float*)carve(HID * NCOL * 4);
    float* Wc2 = (float*)carve(HID * HID * 4);
    float* Vc2 = (float*)carve(HID * HID * 4);
    float* Wc3 = (float*)carve(NCOL * HID * 4);
    float* Vc3 = (float*)carve(NCOL * HID * 4);

    prep_weights<<<240, 256, 0, stream>>>(t1, t2, t3, Wc1, Vc1, Wc2, Vc2, Wc3, Vc3);
    split_lu<<<(M_DIM * M_DIM) / (256 * 8), 256, 0, stream>>>(Lu, Luh, Lul);
    split_x<<<(64 * M_DIM) / (256 * 8), 256, 0, stream>>>(x, Xh, Xl);

    // layer 1: Z1 = x @ Lu^T   (grid 32 blocks)
    gemm_split<<<(M_DIM / GBN) * 1, 256, 0, stream>>>(Xh, Xl, Luh, Lul, Z1, 32, 1);
    mix1<<<(B_SZ * M_DIM) / 256, 256, 0, stream>>>(x, Z1, Wc1, Vc1, b1, H1, H1h, H1l);

    // layer 2: Z2 = H1 @ Lu^T  (480 blocks)
    gemm_split<<<(M_DIM / GBN) * (R2 / GBM), 256, 0, stream>>>(H1h, H1l, Luh, Lul, Z2, R2, R2 / GBM);
    mix2<<<dim3(M_DIM / 128, B_SZ, 2), 256, 0, stream>>>(H1, Z2, Wc2, Vc2, b2, H2, H2h, H2l);

    // layer 3: Z3 = H2 @ Lu^T
    gemm_split<<<(M_DIM / GBN) * (R2 / GBM), 256, 0, stream>>>(H2h, H2l, Luh, Lul, Z3, R2, R2 / GBM);
    mix3<<<(B_SZ * M_DIM) / 256, 256, 0, stream>>>(H2, Z3, Wc3, Vc3, b3, out);
}

// Round 7
// 586.073 us; speedup vs baseline: 1.3304x; 1.0921x over previous
//
#include <hip/hip_runtime.h>

typedef float f32x4 __attribute__((ext_vector_type(4)));
typedef short short8 __attribute__((ext_vector_type(8)));

#define M_DIM 4096
#define B_SZ 4
#define NCOL 8
#define HID 240
#define R2 (B_SZ * HID)          // 960

// bf16 round-to-nearest-even
__device__ __forceinline__ unsigned short bf16_rne(float f) {
    unsigned u = __float_as_uint(f);
    return (unsigned short)((u + 0x7FFFu + ((u >> 16) & 1u)) >> 16);
}
__device__ __forceinline__ float bf16_to_f(unsigned short h) {
    return __uint_as_float(((unsigned)h) << 16);
}

// ---------------------------------------------------------------------------
// prep: Wc1/Vc1 (fp32, mix1), Wc3/Vc3 (fp32, mix3), A2h/A2l (bf16 split of
// stacked [W2|V2], padded to 256 rows x 480 cols, for mix_mfma B-operand).
// ---------------------------------------------------------------------------
__global__ __launch_bounds__(256) void prep_weights(
    const float* __restrict__ t1, const float* __restrict__ t2,
    const float* __restrict__ t3,
    float* __restrict__ Wc1, float* __restrict__ Vc1,
    float* __restrict__ Wc3, float* __restrict__ Vc3,
    short* __restrict__ A2h, short* __restrict__ A2l)
{
    const int n1 = HID * NCOL, n3 = NCOL * HID, nA = 256 * 480;
    int idx = blockIdx.x * blockDim.x + threadIdx.x;
    if (idx < n1) {
        const float* p = t1 + (size_t)idx * 3;
        Wc1[idx] = p[0] + p[1]; Vc1[idx] = p[2];
    } else if (idx < n1 + n3) {
        int j = idx - n1;
        const float* p = t3 + (size_t)j * 3;
        Wc3[j] = p[0] + p[1]; Vc3[j] = p[2];
    } else if (idx < n1 + n3 + nA) {
        int j = idx - n1 - n3;
        int o = j / 480, k = j % 480;
        float val = 0.f;
        if (o < HID) {
            const float* p = t2 + ((size_t)o * HID + (k < HID ? k : k - HID)) * 3;
            val = (k < HID) ? (p[0] + p[1]) : p[2];
        }
        unsigned short hb = bf16_rne(val);
        A2h[j] = (short)hb;
        A2l[j] = (short)bf16_rne(val - bf16_to_f(hb));
    }
}

// ---------------------------------------------------------------------------
// split_lu: Lu fp32 -> (hi, lo) bf16.
// ---------------------------------------------------------------------------
__global__ __launch_bounds__(256) void split_lu(
    const float* __restrict__ Lu, short* __restrict__ Lh, short* __restrict__ Ll)
{
    size_t i8 = ((size_t)blockIdx.x * 256 + threadIdx.x) * 8;
    float4 a = *(const float4*)(Lu + i8);
    float4 b = *(const float4*)(Lu + i8 + 4);
    float v[8] = {a.x, a.y, a.z, a.w, b.x, b.y, b.z, b.w};
    short8 h, l;
    #pragma unroll
    for (int e = 0; e < 8; ++e) {
        unsigned short hb = bf16_rne(v[e]);
        h[e] = (short)hb;
        l[e] = (short)bf16_rne(v[e] - bf16_to_f(hb));
    }
    *(short8*)(Lh + i8) = h;
    *(short8*)(Ll + i8) = l;
}

// ---------------------------------------------------------------------------
// split_x: x (32 x 4096) -> hi/lo bf16 padded to 64 rows (pad rows zero).
// ---------------------------------------------------------------------------
__global__ __launch_bounds__(256) void split_x(
    const float* __restrict__ x, short* __restrict__ Xh, short* __restrict__ Xl)
{
    int t = blockIdx.x * 256 + threadIdx.x;
    size_t i8 = (size_t)t * 8;
    int row = t >> 9;
    short8 h = {0,0,0,0,0,0,0,0}, l = {0,0,0,0,0,0,0,0};
    if (row < B_SZ * NCOL) {
        float4 a = *(const float4*)(x + i8);
        float4 b = *(const float4*)(x + i8 + 4);
        float v[8] = {a.x, a.y, a.z, a.w, b.x, b.y, b.z, b.w};
        #pragma unroll
        for (int e = 0; e < 8; ++e) {
            unsigned short hb = bf16_rne(v[e]);
            h[e] = (short)hb;
            l[e] = (short)bf16_rne(v[e] - bf16_to_f(hb));
        }
    }
    *(short8*)(Xh + i8) = h;
    *(short8*)(Xl + i8) = l;
}

// ---------------------------------------------------------------------------
// gemm_split: C[r,m] = sum_k (Ah+Al)[r,k]*(Bh+Bl)[m,k]  (3-term bf16 split)
// K-loop identical to the r5-validated kernel; only the epilogue varies:
//  MODE 0: fp32 C[row][m]                      (layer 1 -> Z1 for mix1)
//  MODE 1: bf16 h/l transposed AT[b][m][240+i] (layer 2 -> mix_mfma A rows)
//  MODE 2: bf16 h/l C[row][m]                  (layer 3 -> Z3 for mix3)
// ---------------------------------------------------------------------------
#define GBM 64
#define GBN 128
#define GBK 64

template<int MODE>
__global__ __launch_bounds__(256, 2) void gemm_split(
    const short* __restrict__ Ah, const short* __restrict__ Al,
    const short* __restrict__ Bh, const short* __restrict__ Bl,
    float* __restrict__ C, short* __restrict__ Th, short* __restrict__ Tl,
    int R, int NY)
{
    __shared__ short8 lds[3072];
    short8* sAh = lds;
    short8* sAl = lds + 512;
    short8* sBh = lds + 1024;
    short8* sBl = lds + 2048;

    const int tid  = threadIdx.x;
    const int w    = tid >> 6;
    const int lane = tid & 63;
    const int wr   = w >> 1, wc = w & 1;

    int chunk = gridDim.x >> 3;
    int bid = (blockIdx.x & 7) * chunk + (blockIdx.x >> 3);
    int bx = bid / NY;
    int by = bid % NY;
    const int r0 = by * GBM;
    const int m0 = bx * GBN;

    const short* gp[12];
    short8* lp[12];
    #pragma unroll
    for (int j = 0; j < 12; ++j) {
        int g = w * 12 + j;
        const short* base; int c0, row0, seg;
        if (g < 8)       { base = Ah; c0 = g * 64;        row0 = r0; seg = 0;    }
        else if (g < 16) { base = Al; c0 = (g - 8) * 64;  row0 = r0; seg = 512;  }
        else if (g < 32) { base = Bh; c0 = (g - 16) * 64; row0 = m0; seg = 1024; }
        else             { base = Bl; c0 = (g - 32) * 64; row0 = m0; seg = 2048; }
        int c  = c0 + lane;
        int r  = c >> 3;
        int kg = ((c & 7) - r) & 7;
        gp[j] = base + (size_t)(row0 + r) * M_DIM + kg * 8;
        lp[j] = &lds[seg + c0];
    }

    int cA[2][2], cB[2][4];
    #pragma unroll
    for (int s = 0; s < 2; ++s) {
        int kgl = s * 4 + (lane >> 4);
        #pragma unroll
        for (int mi = 0; mi < 2; ++mi) {
            int r = wr * 32 + mi * 16 + (lane & 15);
            cA[s][mi] = r * 8 + ((kgl + r) & 7);
        }
        #pragma unroll
        for (int nj = 0; nj < 4; ++nj) {
            int r = wc * 64 + nj * 16 + (lane & 15);
            cB[s][nj] = r * 8 + ((kgl + r) & 7);
        }
    }

    f32x4 acc[2][4] = {};

    for (int k0 = 0; k0 < M_DIM; k0 += GBK) {
        #pragma unroll
        for (int j = 0; j < 12; ++j)
            __builtin_amdgcn_global_load_lds(
                (const __attribute__((address_space(1))) void*)(gp[j] + k0),
                (__attribute__((address_space(3))) void*)(lp[j]), 16, 0, 0);
        __syncthreads();

        #pragma unroll
        for (int s = 0; s < 2; ++s) {
            short8 ahf[2], alf[2], bhf[4], blf[4];
            #pragma unroll
            for (int mi = 0; mi < 2; ++mi) {
                ahf[mi] = sAh[cA[s][mi]];
                alf[mi] = sAl[cA[s][mi]];
            }
            #pragma unroll
            for (int nj = 0; nj < 4; ++nj) {
                bhf[nj] = sBh[cB[s][nj]];
                blf[nj] = sBl[cB[s][nj]];
            }
            #pragma unroll
            for (int mi = 0; mi < 2; ++mi)
                #pragma unroll
                for (int nj = 0; nj < 4; ++nj) {
                    acc[mi][nj] = __builtin_amdgcn_mfma_f32_16x16x32_bf16(
                        ahf[mi], bhf[nj], acc[mi][nj], 0, 0, 0);
                    acc[mi][nj] = __builtin_amdgcn_mfma_f32_16x16x32_bf16(
                        ahf[mi], blf[nj], acc[mi][nj], 0, 0, 0);
                    acc[mi][nj] = __builtin_amdgcn_mfma_f32_16x16x32_bf16(
                        alf[mi], bhf[nj], acc[mi][nj], 0, 0, 0);
                }
        }
        __syncthreads();
    }

    // epilogue: D row=(lane>>4)*4+q (A-side), col=lane&15 (B-side)
    const int colb = m0 + wc * 64 + (lane & 15);
    #pragma unroll
    for (int mi = 0; mi < 2; ++mi) {
        int rowb = r0 + wr * 32 + mi * 16 + ((lane >> 4) << 2);
        #pragma unroll
        for (int nj = 0; nj < 4; ++nj) {
            int col = colb + nj * 16;
            #pragma unroll
            for (int q = 0; q < 4; ++q) {
                int row = rowb + q;
                if (row < R) {
                    float v = acc[mi][nj][q];
                    if (MODE == 0) {
                        C[(size_t)row * M_DIM + col] = v;
                    } else {
                        unsigned short hb = bf16_rne(v);
                        unsigned short lb = bf16_rne(v - bf16_to_f(hb));
                        if (MODE == 1) {
                            int b = row / HID, i = row % HID;
                            size_t a = ((size_t)(b * M_DIM + col)) * 480 + HID + i;
                            Th[a] = (short)hb; Tl[a] = (short)lb;
                        } else {
                            size_t a = (size_t)row * M_DIM + col;
                            Th[a] = (short)hb; Tl[a] = (short)lb;
                        }
                    }
                }
            }
        }
    }
}

// ---------------------------------------------------------------------------
// mix1: H1 = lrelu(bias1 + W1*x + V1*Z1).  Writes bf16 h/l in BOTH layouts:
//   H1h/H1l [b][o][m]  (gemm2 A-operand)   and  AT2h/l [b*4096+m][0..239]
//   (mix_mfma A-operand, contiguous short8 per thread).
// ---------------------------------------------------------------------------
__global__ __launch_bounds__(256) void mix1(
    const float* __restrict__ x, const float* __restrict__ Z1,
    const float* __restrict__ Wc1, const float* __restrict__ Vc1,
    const float* __restrict__ bias1,
    short* __restrict__ H1h, short* __restrict__ H1l,
    short* __restrict__ ATh, short* __restrict__ ATl)
{
    __shared__ float w[HID * NCOL], v[HID * NCOL], bb[HID];
    for (int i = threadIdx.x; i < HID * NCOL; i += 256) { w[i] = Wc1[i]; v[i] = Vc1[i]; }
    for (int i = threadIdx.x; i < HID; i += 256) bb[i] = bias1[i];
    __syncthreads();

    int gm = blockIdx.x * 256 + threadIdx.x;
    int b = gm >> 12, m = gm & 4095;

    float xv[NCOL], lv[NCOL];
    #pragma unroll
    for (int i = 0; i < NCOL; ++i) {
        xv[i] = x[((size_t)b * NCOL + i) * M_DIM + m];
        lv[i] = Z1[((size_t)b * NCOL + i) * M_DIM + m];
    }
    for (int og = 0; og < HID / 8; ++og) {
        short8 hh, ll;
        #pragma unroll
        for (int j = 0; j < 8; ++j) {
            int o = og * 8 + j;
            float acc = bb[o];
            #pragma unroll
            for (int i = 0; i < NCOL; ++i)
                acc += w[o * NCOL + i] * xv[i] + v[o * NCOL + i] * lv[i];
            acc = acc > 0.f ? acc : 0.01f * acc;
            unsigned short hb = bf16_rne(acc);
            unsigned short lb = bf16_rne(acc - bf16_to_f(hb));
            hh[j] = (short)hb; ll[j] = (short)lb;
            size_t ad = ((size_t)(b * HID + o)) * M_DIM + m;
            H1h[ad] = (short)hb; H1l[ad] = (short)lb;
        }
        size_t at = (size_t)gm * 480 + og * 8;
        *(short8*)(ATh + at) = hh;
        *(short8*)(ATl + at) = ll;
    }
}

// ---------------------------------------------------------------------------
// mix_mfma: layer-2 channel mix as 3-term bf16 MFMA GEMM.
//   C[(b,m), o] = sum_k AT[(b,m), k] * A2[o, k]   (K=480: [H1 | Z2] stacked)
// Block: 256 thr / 4 waves; tile 64 rows (b,m) x 256 cols (o, 240 live).
// K-step 32. Chunk interleave c = r*4 + ((kg + (r>>1))&3): bank-group-
// balanced b128 frag reads AND linear global_load_lds dests.
// Epilogue: +bias2, lrelu, bf16 split -> H2h/H2l [b][o][m].
// ---------------------------------------------------------------------------
__global__ __launch_bounds__(256, 2) void mix_mfma(
    const short* __restrict__ ATh, const short* __restrict__ ATl,
    const short* __restrict__ Bwh, const short* __restrict__ Bwl,
    const float* __restrict__ bias,
    short* __restrict__ Hh, short* __restrict__ Hl)
{
    // Ah/Al: 256 chunks each; Bh/Bl: 1024 chunks each. 40KB total.
    __shared__ short8 lds[2560];
    short8* sAh = lds;
    short8* sAl = lds + 256;
    short8* sBh = lds + 512;
    short8* sBl = lds + 1536;

    const int tid = threadIdx.x, w = tid >> 6, lane = tid & 63;
    int bid = (blockIdx.x & 7) * (gridDim.x >> 3) + (blockIdx.x >> 3);
    const int row0 = bid * 64;                 // (b,m) row base

    const short* gp[10];
    short8* lp[10];
    #pragma unroll
    for (int j = 0; j < 10; ++j) {
        int g = w * 10 + j;                    // 0..39
        const short* base; int c0, seg, rbase;
        if (g < 4)       { base = ATh; c0 = g * 64;        seg = 0;    rbase = row0; }
        else if (g < 8)  { base = ATl; c0 = (g - 4) * 64;  seg = 256;  rbase = row0; }
        else if (g < 24) { base = Bwh; c0 = (g - 8) * 64;  seg = 512;  rbase = 0;    }
        else             { base = Bwl; c0 = (g - 24) * 64; seg = 1536; rbase = 0;    }
        int c = c0 + lane;
        int r = c >> 2, s = c & 3;
        int kg = (s - (r >> 1)) & 3;
        gp[j] = base + (size_t)(rbase + r) * 480 + kg * 8;
        lp[j] = &lds[seg + c0];
    }

    int cA[4], cB[4];
    const int kgl = lane >> 4;
    #pragma unroll
    for (int t = 0; t < 4; ++t) {
        int rA = t * 16 + (lane & 15);
        cA[t] = rA * 4 + ((kgl + (rA >> 1)) & 3);
        int rB = w * 64 + t * 16 + (lane & 15);
        cB[t] = rB * 4 + ((kgl + (rB >> 1)) & 3);
    }

    f32x4 acc[4][4] = {};

    for (int k0 = 0; k0 < 480; k0 += 32) {
        #pragma unroll
        for (int j = 0; j < 10; ++j)
            __builtin_amdgcn_global_load_lds(
                (const __attribute__((address_space(1))) void*)(gp[j] + k0),
                (__attribute__((address_space(3))) void*)(lp[j]), 16, 0, 0);
        __syncthreads();

        short8 bhf[4], blf[4];
        #pragma unroll
        for (int t = 0; t < 4; ++t) { bhf[t] = sBh[cB[t]]; blf[t] = sBl[cB[t]]; }
        #pragma unroll
        for (int mi = 0; mi < 4; ++mi) {
            short8 ahf = sAh[cA[mi]];
            short8 alf = sAl[cA[mi]];
            #pragma unroll
            for (int nj = 0; nj < 4; ++nj) {
                acc[mi][nj] = __builtin_amdgcn_mfma_f32_16x16x32_bf16(
                    ahf, bhf[nj], acc[mi][nj], 0, 0, 0);
                acc[mi][nj] = __builtin_amdgcn_mfma_f32_16x16x32_bf16(
                    ahf, blf[nj], acc[mi][nj], 0, 0, 0);
                acc[mi][nj] = __builtin_amdgcn_mfma_f32_16x16x32_bf16(
                    alf, bhf[nj], acc[mi][nj], 0, 0, 0);
            }
        }
        __syncthreads();
    }

    // epilogue: row (A-side) = row0 + mi*16 + (lane>>4)*4+q; col (B-side) = o
    #pragma unroll
    for (int mi = 0; mi < 4; ++mi) {
        int rowb = row0 + mi * 16 + ((lane >> 4) << 2);
        #pragma unroll
        for (int nj = 0; nj < 4; ++nj) {
            int o = w * 64 + nj * 16 + (lane & 15);
            if (o < HID) {
                float bb = bias[o];
                #pragma unroll
                for (int q = 0; q < 4; ++q) {
                    int row = rowb + q;
                    int b = row >> 12, m = row & 4095;
                    float a = acc[mi][nj][q] + bb;
                    a = a > 0.f ? a : 0.01f * a;
                    unsigned short hb = bf16_rne(a);
                    unsigned short lb = bf16_rne(a - bf16_to_f(hb));
                    size_t ad = ((size_t)(b * HID + o)) * M_DIM + m;
                    Hh[ad] = (short)hb; Hl[ad] = (short)lb;
                }
            }
        }
    }
}

// ---------------------------------------------------------------------------
// mix3: out[b,c,m] = bias3[c] + sum_i W3[c,i]*(H2h+H2l)[b,i,m]
//                              + V3[c,i]*(Z3h+Z3l)[b,i,m]   (no activation)
// ---------------------------------------------------------------------------
__global__ __launch_bounds__(256) void mix3(
    const unsigned short* __restrict__ H2h, const unsigned short* __restrict__ H2l,
    const unsigned short* __restrict__ Z3h, const unsigned short* __restrict__ Z3l,
    const float* __restrict__ Wc3, const float* __restrict__ Vc3,
    const float* __restrict__ bias3, float* __restrict__ out)
{
    __shared__ float w[NCOL * HID], v[NCOL * HID];
    for (int i = threadIdx.x; i < NCOL * HID; i += 256) { w[i] = Wc3[i]; v[i] = Vc3[i]; }
    __syncthreads();

    int gm = blockIdx.x * 256 + threadIdx.x;
    int b = gm >> 12, m = gm & 4095;

    float acc[NCOL];
    #pragma unroll
    for (int c = 0; c < NCOL; ++c) acc[c] = bias3[c];

    for (int i = 0; i < HID; ++i) {
        size_t ad = ((size_t)(b * HID + i)) * M_DIM + m;
        float h = bf16_to_f(H2h[ad]) + bf16_to_f(H2l[ad]);
        float z = bf16_to_f(Z3h[ad]) + bf16_to_f(Z3l[ad]);
        #pragma unroll
        for (int c = 0; c < NCOL; ++c)
            acc[c] += w[c * HID + i] * h + v[c * HID + i] * z;
    }
    #pragma unroll
    for (int c = 0; c < NCOL; ++c)
        out[((size_t)b * NCOL + c) * M_DIM + m] = acc[c];
}

// ---------------------------------------------------------------------------
extern "C" void kernel_launch(void* const* d_in, const int* in_sizes, int n_in,
                              void* d_out, int out_size, void* d_ws, size_t ws_size,
                              hipStream_t stream)
{
    // inputs: Ll, Lu, x, theta1, bias1, theta2, bias2, theta3, bias3
    const float* Lu = (const float*)d_in[1];
    const float* x  = (const float*)d_in[2];
    const float* t1 = (const float*)d_in[3];
    const float* b1 = (const float*)d_in[4];
    const float* t2 = (const float*)d_in[5];
    const float* b2 = (const float*)d_in[6];
    const float* t3 = (const float*)d_in[7];
    const float* b3 = (const float*)d_in[8];
    float* out = (float*)d_out;

    // workspace carve-up (256B aligned)
    char* p = (char*)d_ws;
    auto carve = [&](size_t bytes) { char* r = p; p += (bytes + 255) & ~(size_t)255; return r; };
    short* Luh  = (short*)carve((size_t)M_DIM * M_DIM * 2);
    short* Lul  = (short*)carve((size_t)M_DIM * M_DIM * 2);
    short* Xh   = (short*)carve((size_t)64 * M_DIM * 2);
    short* Xl   = (short*)carve((size_t)64 * M_DIM * 2);
    float* Z1   = (float*)carve((size_t)32 * M_DIM * 4);
    short* H1h  = (short*)carve((size_t)R2 * M_DIM * 2);
    short* H1l  = (short*)carve((size_t)R2 * M_DIM * 2);
    short* AT2h = (short*)carve((size_t)B_SZ * M_DIM * 480 * 2);
    short* AT2l = (short*)carve((size_t)B_SZ * M_DIM * 480 * 2);
    short* H2h  = (short*)carve((size_t)R2 * M_DIM * 2);
    short* H2l  = (short*)carve((size_t)R2 * M_DIM * 2);
    short* Z3h  = (short*)carve((size_t)R2 * M_DIM * 2);
    short* Z3l  = (short*)carve((size_t)R2 * M_DIM * 2);
    short* A2h  = (short*)carve((size_t)256 * 480 * 2);
    short* A2l  = (short*)carve((size_t)256 * 480 * 2);
    float* Wc1  = (float*)carve(HID * NCOL * 4);
    float* Vc1  = (float*)carve(HID * NCOL * 4);
    float* Wc3  = (float*)carve(NCOL * HID * 4);
    float* Vc3  = (float*)carve(NCOL * HID * 4);

    prep_weights<<<496, 256, 0, stream>>>(t1, t2, t3, Wc1, Vc1, Wc3, Vc3, A2h, A2l);
    split_lu<<<(M_DIM * M_DIM) / (256 * 8), 256, 0, stream>>>(Lu, Luh, Lul);
    split_x<<<(64 * M_DIM) / (256 * 8), 256, 0, stream>>>(x, Xh, Xl);

    // layer 1: Z1 = x @ Lu^T (fp32 out), then VALU mix -> H1 splits + AT2[0..239]
    gemm_split<0><<<(M_DIM / GBN) * 1, 256, 0, stream>>>(
        Xh, Xl, Luh, Lul, Z1, nullptr, nullptr, 32, 1);
    mix1<<<(B_SZ * M_DIM) / 256, 256, 0, stream>>>(
        x, Z1, Wc1, Vc1, b1, H1h, H1l, AT2h, AT2l);

    // layer 2: Z2 (bf16, transposed into AT2[240..479]), then MFMA mix -> H2 splits
    gemm_split<1><<<(M_DIM / GBN) * (R2 / GBM), 256, 0, stream>>>(
        H1h, H1l, Luh, Lul, nullptr, AT2h, AT2l, R2, R2 / GBM);
    mix_mfma<<<(B_SZ * M_DIM) / 64, 256, 0, stream>>>(
        AT2h, AT2l, A2h, A2l, b2, H2h, H2l);

    // layer 3: Z3 (bf16 h/l, row layout), then VALU mix -> out
    gemm_split<2><<<(M_DIM / GBN) * (R2 / GBM), 256, 0, stream>>>(
        H2h, H2l, Luh, Lul, nullptr, Z3h, Z3l, R2, R2 / GBM);
    mix3<<<(B_SZ * M_DIM) / 256, 256, 0, stream>>>(
        (const unsigned short*)H2h, (const unsigned short*)H2l,
        (const unsigned short*)Z3h, (const unsigned short*)Z3l,
        Wc3, Vc3, b3, out);
}